// Round 12
// baseline (216.041 us; speedup 1.0000x reference)
//
#include <hip/hip_runtime.h>
#include <math.h>

#define B_ 2
#define C_ 1024
#define D_ 1024
#define H_ 16
#define DH_ 64
#define EPSF 1e-8f

typedef __bf16 bf16;
typedef __attribute__((ext_vector_type(4))) __bf16 bf16x4;
typedef __attribute__((ext_vector_type(8))) __bf16 bf16x8;
typedef __attribute__((ext_vector_type(4))) float f32x4;

__device__ inline f32x4 mfma16(bf16x8 a, bf16x8 b, f32x4 c) {
  return __builtin_amdgcn_mfma_f32_16x16x32_bf16(a, b, c, 0, 0, 0);
}

__device__ inline void async16(const bf16* g, bf16* l) {
  __builtin_amdgcn_global_load_lds((const __attribute__((address_space(1))) void*)g,
                                   (__attribute__((address_space(3))) void*)l, 16, 0, 0);
}

// Raw barrier + counted vmcnt (T4).
#define S_BARRIER() asm volatile("s_barrier" ::: "memory")
#define S_VMCNT(N) asm volatile("s_waitcnt vmcnt(" #N ")" ::: "memory")

// theta for rope pair index i (reference uses (i-1)): 10000^(-2(i-1)/64)
__device__ inline float rope_theta(float i) {
  return exp2f(-13.287712379549449f * (2.0f * (i - 1.0f) * (1.0f / 64.0f)));
}

// ---------------- fused: weight cvt (segs 0..6) + RMSNorm fp32->bf16 (blocks 7168+) ----------------
__global__ __launch_bounds__(256) void cvt_rms_kernel(const float* __restrict__ wqkv,
                                                      const float* __restrict__ wout,
                                                      const float* __restrict__ wf,
                                                      const float* __restrict__ www,
                                                      const float* __restrict__ wv,
                                                      bf16* __restrict__ wdst,
                                                      const float* __restrict__ x,
                                                      const float* __restrict__ rw,
                                                      const float* __restrict__ rb,
                                                      bf16* __restrict__ xout) {
  __shared__ float red[4];
  int t = threadIdx.x;
  if (blockIdx.x < 7 * 1024) {
    int seg = blockIdx.x >> 10;
    int local = (blockIdx.x & 1023) * 1024 + t * 4;
    const float* src = seg < 3 ? wqkv + (size_t)seg * (D_ * D_)
                     : seg == 3 ? wout : seg == 4 ? wf : seg == 5 ? www : wv;
    float4 v = *(const float4*)(src + local);
    bf16x4 o;
    o[0] = (bf16)v.x; o[1] = (bf16)v.y; o[2] = (bf16)v.z; o[3] = (bf16)v.w;
    *(bf16x4*)(wdst + (size_t)seg * (D_ * D_) + local) = o;
    return;
  }
  int row = blockIdx.x - 7 * 1024;
  int c = row & (C_ - 1);
  float4 xv = *(const float4*)(x + (size_t)row * D_ + t * 4);
  float ss = xv.x * xv.x + xv.y * xv.y + xv.z * xv.z + xv.w * xv.w;
#pragma unroll
  for (int m = 1; m < 64; m <<= 1) ss += __shfl_xor(ss, m, 64);
  if ((t & 63) == 0) red[t >> 6] = ss;
  __syncthreads();
  float tot = red[0] + red[1] + red[2] + red[3];
  float inv = rsqrtf(tot * (1.0f / D_) + EPSF);
  float4 wv4 = *(const float4*)(rw + (size_t)c * D_ + t * 4);
  float4 bv4 = *(const float4*)(rb + (size_t)c * D_ + t * 4);
  bf16x4 ov;
  ov[0] = (bf16)(wv4.x * (xv.x * inv) + bv4.x);
  ov[1] = (bf16)(wv4.y * (xv.y * inv) + bv4.y);
  ov[2] = (bf16)(wv4.z * (xv.z * inv) + bv4.z);
  ov[3] = (bf16)(wv4.w * (xv.w * inv) + bv4.w);
  *(bf16x4*)(xout + (size_t)row * D_ + t * 4) = ov;
}

// ---------------- RMSNorm (bf16 in, bf16 out) ----------------
__global__ __launch_bounds__(256) void rmsnorm_bf16_kernel(const bf16* __restrict__ x,
                                                           const float* __restrict__ w,
                                                           const float* __restrict__ b,
                                                           bf16* __restrict__ out) {
  int row = blockIdx.x;
  int c = row & (C_ - 1);
  int t = threadIdx.x;
  bf16x4 xv = *(const bf16x4*)(x + (size_t)row * D_ + t * 4);
  float f0 = (float)xv[0], f1 = (float)xv[1], f2 = (float)xv[2], f3 = (float)xv[3];
  float ss = f0 * f0 + f1 * f1 + f2 * f2 + f3 * f3;
#pragma unroll
  for (int m = 1; m < 64; m <<= 1) ss += __shfl_xor(ss, m, 64);
  __shared__ float red[4];
  if ((t & 63) == 0) red[t >> 6] = ss;
  __syncthreads();
  float tot = red[0] + red[1] + red[2] + red[3];
  float inv = rsqrtf(tot * (1.0f / D_) + EPSF);
  float4 wv = *(const float4*)(w + (size_t)c * D_ + t * 4);
  float4 bv = *(const float4*)(b + (size_t)c * D_ + t * 4);
  bf16x4 ov;
  ov[0] = (bf16)(wv.x * (f0 * inv) + bv.x);
  ov[1] = (bf16)(wv.y * (f1 * inv) + bv.y);
  ov[2] = (bf16)(wv.z * (f2 * inv) + bv.z);
  ov[3] = (bf16)(wv.w * (f3 * inv) + bv.w);
  *(bf16x4*)(out + (size_t)row * D_ + t * 4) = ov;
}

// ---------------- generic GEMM <128,64>: EXACT r7/r9-verified qkv K-loop structure
// (BK=64, 4+2 staging, vmcnt(6), wm=(w>>1)*64 mapping); only the epilogue differs
// (bias + optional residual instead of qkv/V-transpose writes). ----------------
template <int BMt, int BNt>
__global__ __launch_bounds__(256) void gemm_lds(const bf16* __restrict__ A,
                                                const bf16* __restrict__ W,
                                                const float* __restrict__ bias,
                                                const bf16* __restrict__ R,
                                                bf16* __restrict__ Cout,
                                                int M, int N, int K) {
  constexpr int BK = 64;
  constexpr int MT = BMt / 32;
  constexpr int NT = BNt / 32;
  __shared__ bf16 sa[2][BMt * BK];
  __shared__ bf16 sb[2][BNt * BK];
  int t = threadIdx.x, l = t & 63, w = t >> 6;
  int m0 = blockIdx.y * BMt;
  int n0 = blockIdx.x * BNt;
  int wm = (w >> 1) * (BMt / 2), wn = (w & 1) * (BNt / 2);
  int lm = l & 15, lq = l >> 4;
  int swz = lm & 7;
  f32x4 acc[MT][NT] = {};

  auto stage = [&](int buf, int k0) {
#pragma unroll
    for (int p = 0; p < BMt / 32; ++p) {
      int lin = p * 256 + t;
      int r = lin >> 3, cc = (lin & 7) ^ (r & 7);
      async16(A + (size_t)(m0 + r) * K + k0 + cc * 8, &sa[buf][lin * 8]);
    }
#pragma unroll
    for (int p = 0; p < BNt / 32; ++p) {
      int lin = p * 256 + t;
      int r = lin >> 3, cc = (lin & 7) ^ (r & 7);
      async16(W + (size_t)(n0 + r) * K + k0 + cc * 8, &sb[buf][lin * 8]);
    }
  };  // 6 vmem instructions per wave for <128,64>

  int NKi = K / BK;
  stage(0, 0);
  int cur = 0;
  for (int i = 0; i < NKi; ++i) {
    if (i + 1 < NKi) {
      stage(cur ^ 1, (i + 1) * BK);
      S_VMCNT(6);
    } else {
      S_VMCNT(0);
    }
    S_BARRIER();
    bf16x8 af[MT][2], bfr[NT][2];
#pragma unroll
    for (int mt = 0; mt < MT; ++mt) {
      const bf16* base = &sa[cur][0] + (wm + mt * 16 + lm) * BK;
      af[mt][0] = *(const bf16x8*)(base + ((lq ^ swz) << 3));
      af[mt][1] = *(const bf16x8*)(base + (((4 | lq) ^ swz) << 3));
    }
#pragma unroll
    for (int nt = 0; nt < NT; ++nt) {
      const bf16* base = &sb[cur][0] + (wn + nt * 16 + lm) * BK;
      bfr[nt][0] = *(const bf16x8*)(base + ((lq ^ swz) << 3));
      bfr[nt][1] = *(const bf16x8*)(base + (((4 | lq) ^ swz) << 3));
    }
#pragma unroll
    for (int mt = 0; mt < MT; ++mt)
#pragma unroll
      for (int nt = 0; nt < NT; ++nt) {
        acc[mt][nt] = mfma16(af[mt][0], bfr[nt][0], acc[mt][nt]);
        acc[mt][nt] = mfma16(af[mt][1], bfr[nt][1], acc[mt][nt]);
      }
    S_BARRIER();
    cur ^= 1;
  }
#pragma unroll
  for (int mt = 0; mt < MT; ++mt)
#pragma unroll
    for (int nt = 0; nt < NT; ++nt) {
      int col = n0 + wn + nt * 16 + lm;
      float bb = bias ? bias[col] : 0.0f;
#pragma unroll
      for (int r = 0; r < 4; ++r) {
        int row = m0 + wm + mt * 16 + lq * 4 + r;
        float v = acc[mt][nt][r] + bb;
        if (R) v += (float)R[(size_t)row * N + col];
        Cout[(size_t)row * N + col] = (bf16)v;
      }
    }
}

// ---------------- QKV GEMM <128,64> BK=64, dbuf counted-vmcnt; V-transpose epilogue (r9 exact) ----------------
__global__ __launch_bounds__(256) void gemm_qkv_kernel(const bf16* __restrict__ A,
                                                       const bf16* __restrict__ W,
                                                       bf16* __restrict__ qkv,
                                                       bf16* __restrict__ vt) {
  constexpr int BK = 64;
  constexpr int BMt = 128, BNt = 64, MT = 4, NT = 2;
  const int N = 3 * D_, K = D_;
  __shared__ bf16 sa[2][BMt * BK];
  __shared__ bf16 sb[2][BNt * BK];
  int t = threadIdx.x, l = t & 63, w = t >> 6;
  int m0 = blockIdx.y * BMt;
  int n0 = blockIdx.x * BNt;
  int wm = (w >> 1) * 64, wn = (w & 1) * 32;
  int lm = l & 15, lq = l >> 4;
  int swz = lm & 7;
  f32x4 acc[MT][NT] = {};

  auto stage = [&](int buf, int k0) {
#pragma unroll
    for (int p = 0; p < 4; ++p) {
      int lin = p * 256 + t;
      int r = lin >> 3, cc = (lin & 7) ^ (r & 7);
      async16(A + (size_t)(m0 + r) * K + k0 + cc * 8, &sa[buf][lin * 8]);
    }
#pragma unroll
    for (int p = 0; p < 2; ++p) {
      int lin = p * 256 + t;
      int r = lin >> 3, cc = (lin & 7) ^ (r & 7);
      async16(W + (size_t)(n0 + r) * K + k0 + cc * 8, &sb[buf][lin * 8]);
    }
  };  // 6 vmem instructions per wave

  int NKi = K / BK;
  stage(0, 0);
  int cur = 0;
  for (int i = 0; i < NKi; ++i) {
    if (i + 1 < NKi) {
      stage(cur ^ 1, (i + 1) * BK);
      S_VMCNT(6);
    } else {
      S_VMCNT(0);
    }
    S_BARRIER();
    bf16x8 af[MT][2], bfr[NT][2];
#pragma unroll
    for (int mt = 0; mt < MT; ++mt) {
      const bf16* base = &sa[cur][0] + (wm + mt * 16 + lm) * BK;
      af[mt][0] = *(const bf16x8*)(base + ((lq ^ swz) << 3));
      af[mt][1] = *(const bf16x8*)(base + (((4 | lq) ^ swz) << 3));
    }
#pragma unroll
    for (int nt = 0; nt < NT; ++nt) {
      const bf16* base = &sb[cur][0] + (wn + nt * 16 + lm) * BK;
      bfr[nt][0] = *(const bf16x8*)(base + ((lq ^ swz) << 3));
      bfr[nt][1] = *(const bf16x8*)(base + (((4 | lq) ^ swz) << 3));
    }
#pragma unroll
    for (int mt = 0; mt < MT; ++mt)
#pragma unroll
      for (int nt = 0; nt < NT; ++nt) {
        acc[mt][nt] = mfma16(af[mt][0], bfr[nt][0], acc[mt][nt]);
        acc[mt][nt] = mfma16(af[mt][1], bfr[nt][1], acc[mt][nt]);
      }
    S_BARRIER();
    cur ^= 1;
  }
  if (n0 < 2 * D_) {
#pragma unroll
    for (int mt = 0; mt < MT; ++mt)
#pragma unroll
      for (int nt = 0; nt < NT; ++nt) {
        int col = n0 + wn + nt * 16 + lm;
#pragma unroll
        for (int r = 0; r < 4; ++r) {
          int row = m0 + wm + mt * 16 + lq * 4 + r;
          qkv[(size_t)row * N + col] = (bf16)acc[mt][nt][r];
        }
      }
  } else {
    bf16* tv = &sa[0][0];  // 64*136 = 8704 elems; all compute done (final barrier passed)
#pragma unroll
    for (int mt = 0; mt < MT; ++mt)
#pragma unroll
      for (int nt = 0; nt < NT; ++nt) {
        int dh = wn + nt * 16 + lm;
#pragma unroll
        for (int r = 0; r < 4; ++r)
          tv[dh * 136 + wm + mt * 16 + lq * 4 + r] = (bf16)acc[mt][nt][r];
      }
    __syncthreads();
    int h = (n0 - 2 * D_) >> 6;
    int bb = m0 >> 10;
    int mloc = m0 & 1023;
    size_t vbase = (size_t)((bb * H_ + h) * DH_) * C_;
#pragma unroll
    for (int p = 0; p < 4; ++p) {
      int lin = p * 256 + t;
      int dh = lin >> 4;
      int mm = (lin & 15) * 8;
      *(int4*)(vt + vbase + (size_t)dh * C_ + mloc + mm) = *(int4*)(tv + dh * 136 + mm);
    }
  }
}

// ---------------- Fused FFN tail: BK=64, dbuf counted-vmcnt (r9 exact) ----------------
__global__ __launch_bounds__(256) void gemm_ffn_kernel(const bf16* __restrict__ A,
                                                       const bf16* __restrict__ Ww,
                                                       const bf16* __restrict__ Wv,
                                                       const float* __restrict__ bw,
                                                       const float* __restrict__ bv,
                                                       const bf16* __restrict__ x3,
                                                       const float* __restrict__ beta_p,
                                                       float* __restrict__ out) {
  constexpr int BK = 64;
  __shared__ bf16 sa[2][64 * BK];
  __shared__ bf16 sb1[2][64 * BK];
  __shared__ bf16 sb2[2][64 * BK];
  int t = threadIdx.x, l = t & 63, w = t >> 6;
  int m0 = blockIdx.y * 64, n0 = blockIdx.x * 64;
  int wm = (w >> 1) * 32, wn = (w & 1) * 32;
  int lm = l & 15, lq = l >> 4;
  int swz = lm & 7;
  float beta = beta_p[0];
  f32x4 acc1[2][2] = {}, acc2[2][2] = {};

  auto stage = [&](int buf, int k0) {
#pragma unroll
    for (int p = 0; p < 2; ++p) {
      int lin = p * 256 + t;
      int r = lin >> 3, cc = (lin & 7) ^ (r & 7);
      async16(A + (size_t)(m0 + r) * D_ + k0 + cc * 8, &sa[buf][lin * 8]);
      async16(Ww + (size_t)(n0 + r) * D_ + k0 + cc * 8, &sb1[buf][lin * 8]);
      async16(Wv + (size_t)(n0 + r) * D_ + k0 + cc * 8, &sb2[buf][lin * 8]);
    }
  };  // 6 vmem instructions per wave

  int NKi = D_ / BK;
  stage(0, 0);
  int cur = 0;
  for (int i = 0; i < NKi; ++i) {
    if (i + 1 < NKi) {
      stage(cur ^ 1, (i + 1) * BK);
      S_VMCNT(6);
    } else {
      S_VMCNT(0);
    }
    S_BARRIER();
    bf16x8 af[2][2], b1f[2][2], b2f[2][2];
#pragma unroll
    for (int mt = 0; mt < 2; ++mt) {
      const bf16* base = &sa[cur][0] + (wm + mt * 16 + lm) * BK;
      af[mt][0] = *(const bf16x8*)(base + ((lq ^ swz) << 3));
      af[mt][1] = *(const bf16x8*)(base + (((4 | lq) ^ swz) << 3));
    }
#pragma unroll
    for (int nt = 0; nt < 2; ++nt) {
      const bf16* base1 = &sb1[cur][0] + (wn + nt * 16 + lm) * BK;
      const bf16* base2 = &sb2[cur][0] + (wn + nt * 16 + lm) * BK;
      b1f[nt][0] = *(const bf16x8*)(base1 + ((lq ^ swz) << 3));
      b1f[nt][1] = *(const bf16x8*)(base1 + (((4 | lq) ^ swz) << 3));
      b2f[nt][0] = *(const bf16x8*)(base2 + ((lq ^ swz) << 3));
      b2f[nt][1] = *(const bf16x8*)(base2 + (((4 | lq) ^ swz) << 3));
    }
#pragma unroll
    for (int mt = 0; mt < 2; ++mt)
#pragma unroll
      for (int nt = 0; nt < 2; ++nt) {
        acc1[mt][nt] = mfma16(af[mt][0], b1f[nt][0], acc1[mt][nt]);
        acc1[mt][nt] = mfma16(af[mt][1], b1f[nt][1], acc1[mt][nt]);
        acc2[mt][nt] = mfma16(af[mt][0], b2f[nt][0], acc2[mt][nt]);
        acc2[mt][nt] = mfma16(af[mt][1], b2f[nt][1], acc2[mt][nt]);
      }
    S_BARRIER();
    cur ^= 1;
  }
#pragma unroll
  for (int mt = 0; mt < 2; ++mt)
#pragma unroll
    for (int nt = 0; nt < 2; ++nt) {
      int col = n0 + wn + nt * 16 + lm;
      float bbw = bw[col], bbv = bv[col];
#pragma unroll
      for (int r = 0; r < 4; ++r) {
        int row = m0 + wm + mt * 16 + lq * 4 + r;
        float z = acc1[mt][nt][r] + bbw;
        float g = acc2[mt][nt][r] + bbv;
        float sw_ = z / (1.0f + __expf(-beta * z));
        out[(size_t)row * D_ + col] = (float)x3[(size_t)row * D_ + col] + sw_ * g;
      }
    }
}

// ---------------- Fused attention v10 (r9 exact: dbuf K/Kr/V, one barrier per j-tile) ----------------
__global__ __launch_bounds__(256) void attn_kernel(const bf16* __restrict__ qkv,
                                                   const bf16* __restrict__ vt,
                                                   bf16* __restrict__ y) {
  __shared__ bf16 sk[2][64 * 72];
  __shared__ bf16 skr[2][64 * 72];
  __shared__ bf16 sv[2][64 * 72];
  __shared__ bf16 pl[4][16 * 72];
  int t = threadIdx.x, l = t & 63, w = t >> 6;
  int blk = blockIdx.x;  // 512
  int idx = blk & 255;
  int it = (blk < 256) ? (idx >> 5) : (15 - (idx >> 5));  // balanced (k,15-k) CU pairs
  int r5 = idx & 31;
  int b = r5 >> 4;
  int h = r5 & 15;
  int i_base = it * 64 + w * 16;
  int lm = l & 15, lq = l >> 4;
  const float scale = 0.125f;

  size_t hq = (size_t)h * DH_;
  size_t qrow = (size_t)(b * C_ + i_base + lm) * (3 * D_) + hq;
  bf16x8 qp[2], qrf[2];
  float cq = (float)(i_base + lm);
#pragma unroll
  for (int kk = 0; kk < 2; ++kk) {
    qp[kk] = *(const bf16x8*)(qkv + qrow + kk * 32 + lq * 8);
#pragma unroll
    for (int j = 0; j < 4; ++j) {
      float ip = (float)(kk * 16 + lq * 4 + j);
      float ang = cq * rope_theta(ip);
      float sv_, cv_;
      __sincosf(ang, &sv_, &cv_);
      float qe = (float)qp[kk][2 * j], qo = (float)qp[kk][2 * j + 1];
      qrf[kk][2 * j] = (bf16)(qe * cv_ + qo * sv_);
      qrf[kk][2 * j + 1] = (bf16)(qo * cv_ - qe * sv_);
    }
  }

  float den[4] = {0.f, 0.f, 0.f, 0.f};
  f32x4 yacc[4] = {};
  int i_max = i_base + 15;
  size_t kbase = (size_t)(b * C_) * (3 * D_) + D_ + hq;
  size_t vtbase = (size_t)((b * H_ + h) * DH_) * C_;
  int sr = t >> 3;
  int sc = (t & 7) * 8;
  float th0 = rope_theta((float)((sc >> 1) + 0));
  float th1 = rope_theta((float)((sc >> 1) + 1));
  float th2 = rope_theta((float)((sc >> 1) + 2));
  float th3 = rope_theta((float)((sc >> 1) + 3));

  int4 pk0, pk1, pv0, pv1, rk0, rk1;
#define FETCH_TILE(J0)                                                          \
  pk0 = *(const int4*)(qkv + kbase + (size_t)((J0) + sr) * (3 * D_) + sc);      \
  pk1 = *(const int4*)(qkv + kbase + (size_t)((J0) + 32 + sr) * (3 * D_) + sc); \
  pv0 = *(const int4*)(vt + vtbase + (size_t)sr * C_ + (J0) + sc);              \
  pv1 = *(const int4*)(vt + vtbase + (size_t)(32 + sr) * C_ + (J0) + sc);

#define ROTP(KV, RV, P)                                       \
  {                                                           \
    float e = (float)KV[2 * P], o = (float)KV[2 * P + 1];     \
    RV[2 * P] = (bf16)(e * c_ + o * s_);                      \
    RV[2 * P + 1] = (bf16)(o * c_ - e * s_);                  \
  }
#define ROTATE(J0)                                            \
  {                                                           \
    bf16x8 k0 = *(bf16x8*)&pk0, k1 = *(bf16x8*)&pk1;          \
    bf16x8 r0, r1;                                            \
    float jA = (float)((J0) + sr), jB = (float)((J0) + 32 + sr); \
    float s_, c_;                                             \
    __sincosf(jA * th0, &s_, &c_); ROTP(k0, r0, 0)            \
    __sincosf(jA * th1, &s_, &c_); ROTP(k0, r0, 1)            \
    __sincosf(jA * th2, &s_, &c_); ROTP(k0, r0, 2)            \
    __sincosf(jA * th3, &s_, &c_); ROTP(k0, r0, 3)            \
    __sincosf(jB * th0, &s_, &c_); ROTP(k1, r1, 0)            \
    __sincosf(jB * th1, &s_, &c_); ROTP(k1, r1, 1)            \
    __sincosf(jB * th2, &s_, &c_); ROTP(k1, r1, 2)            \
    __sincosf(jB * th3, &s_, &c_); ROTP(k1, r1, 3)            \
    rk0 = *(int4*)&r0;                                        \
    rk1 = *(int4*)&r1;                                        \
  }

  FETCH_TILE(0)
  ROTATE(0)

  for (int j0 = 0; j0 < C_; j0 += 64) {
    int bu = (j0 >> 6) & 1;
    *(int4*)(&sk[bu][0] + sr * 72 + sc) = pk0;
    *(int4*)(&sk[bu][0] + (32 + sr) * 72 + sc) = pk1;
    *(int4*)(&skr[bu][0] + sr * 72 + sc) = rk0;
    *(int4*)(&skr[bu][0] + (32 + sr) * 72 + sc) = rk1;
    *(int4*)(&sv[bu][0] + sr * 72 + sc) = pv0;
    *(int4*)(&sv[bu][0] + (32 + sr) * 72 + sc) = pv1;
    __syncthreads();  // single barrier per tile: publishes buf[bu]
    if (j0 + 64 < C_) {
      FETCH_TILE(j0 + 64)
    }
    // denominator: unrotated q.k over all j
#pragma unroll
    for (int js = 0; js < 64; js += 16) {
      bf16x8 kf0 = *(const bf16x8*)(&sk[bu][0] + (js + lm) * 72 + lq * 8);
      bf16x8 kf1 = *(const bf16x8*)(&sk[bu][0] + (js + lm) * 72 + 32 + lq * 8);
      f32x4 s = {0.f, 0.f, 0.f, 0.f};
      s = mfma16(qp[0], kf0, s);
      s = mfma16(qp[1], kf1, s);
#pragma unroll
      for (int r = 0; r < 4; ++r) den[r] += __expf(s[r] * scale);
    }
    // numerator + PV: causal tiles only (wave-uniform guard)
    if (j0 <= i_max) {
#pragma unroll
      for (int js = 0; js < 64; js += 16) {
        bf16x8 kf0 = *(const bf16x8*)(&skr[bu][0] + (js + lm) * 72 + lq * 8);
        bf16x8 kf1 = *(const bf16x8*)(&skr[bu][0] + (js + lm) * 72 + 32 + lq * 8);
        f32x4 s = {0.f, 0.f, 0.f, 0.f};
        s = mfma16(qrf[0], kf0, s);
        s = mfma16(qrf[1], kf1, s);
#pragma unroll
        for (int r = 0; r < 4; ++r) {
          int jg = j0 + js + lm;
          int ig = i_base + lq * 4 + r;
          float p = (jg <= ig) ? __expf(s[r] * scale) : 0.0f;
          pl[w][(lq * 4 + r) * 72 + js + lm] = (bf16)p;
        }
      }
      __builtin_amdgcn_wave_barrier();
      bf16x8 pf0 = *(const bf16x8*)(pl[w] + lm * 72 + lq * 8);
      bf16x8 pf1 = *(const bf16x8*)(pl[w] + lm * 72 + 32 + lq * 8);
#pragma unroll
      for (int tt = 0; tt < 4; ++tt) {
        bf16x8 vf0 = *(const bf16x8*)(&sv[bu][0] + (tt * 16 + lm) * 72 + lq * 8);
        bf16x8 vf1 = *(const bf16x8*)(&sv[bu][0] + (tt * 16 + lm) * 72 + 32 + lq * 8);
        yacc[tt] = mfma16(pf0, vf0, mfma16(pf1, vf1, yacc[tt]));
      }
      __builtin_amdgcn_wave_barrier();
    }
    // rotate NEXT tile's K (loads landed during compute; pure VALU, off the serial path)
    if (j0 + 64 < C_) {
      ROTATE(j0 + 64)
    }
  }
#undef FETCH_TILE
#undef ROTATE
#undef ROTP
  // normalize in-register and write y directly (no combine pass)
  float inv[4];
#pragma unroll
  for (int r = 0; r < 4; ++r) {
    float d = den[r];
    d += __shfl_xor(d, 1, 64);
    d += __shfl_xor(d, 2, 64);
    d += __shfl_xor(d, 4, 64);
    d += __shfl_xor(d, 8, 64);
    inv[r] = 1.0f / d;
  }
#pragma unroll
  for (int tt = 0; tt < 4; ++tt)
#pragma unroll
    for (int r = 0; r < 4; ++r) {
      int ig = i_base + lq * 4 + r;
      y[(size_t)(b * C_ + ig) * D_ + hq + tt * 16 + lm] = (bf16)(yacc[tt][r] * inv[r]);
    }
}

extern "C" void kernel_launch(void* const* d_in, const int* in_sizes, int n_in,
                              void* d_out, int out_size, void* d_ws, size_t ws_size,
                              hipStream_t stream) {
  const float* x = (const float*)d_in[0];
  const float* rms_w = (const float*)d_in[1];
  const float* rms_b = (const float*)d_in[2];
  const float* Wqkv = (const float*)d_in[3];
  const float* Wout = (const float*)d_in[4];
  const float* bout = (const float*)d_in[5];
  const float* Wf = (const float*)d_in[6];
  const float* bfp = (const float*)d_in[7];
  const float* Ww = (const float*)d_in[8];
  const float* bw = (const float*)d_in[9];
  const float* Wv = (const float*)d_in[10];
  const float* bv = (const float*)d_in[11];
  const float* beta = (const float*)d_in[12];
  float* out = (float*)d_out;

  bf16* ws = (bf16*)d_ws;
  const size_t DD = (size_t)D_ * D_;
  const size_t MC = (size_t)B_ * C_;
  bf16* wb = ws;            // 7DD: Wqkv(3), Wout, Wf, Ww, Wv
  bf16* x1 = ws + 7 * DD;
  bf16* qkv = ws + 9 * DD;
  bf16* vt = ws + 15 * DD;
  bf16* x2 = ws + 17 * DD;
  bf16* x3 = ws + 19 * DD;
  bf16* hbuf = ws + 21 * DD;
  bf16* y = (bf16*)d_out;   // bf16 y inside fp32 d_out; consumed before final write

  cvt_rms_kernel<<<7 * 1024 + MC, 256, 0, stream>>>(Wqkv, Wout, Wf, Ww, Wv, wb, x, rms_w,
                                                    rms_b, x1);
  gemm_qkv_kernel<<<dim3(3 * D_ / 64, MC / 128), 256, 0, stream>>>(x1, wb, qkv, vt);
  attn_kernel<<<B_ * H_ * 16, 256, 0, stream>>>(qkv, vt, y);
  gemm_lds<128, 64><<<dim3(D_ / 64, MC / 128), 256, 0, stream>>>(
      y, wb + 3 * DD, bout, x1, x2, MC, D_, D_);
  rmsnorm_bf16_kernel<<<MC, 256, 0, stream>>>(x2, rms_w, rms_b, x3);
  gemm_lds<128, 64><<<dim3(D_ / 64, MC / 128), 256, 0, stream>>>(
      x3, wb + 4 * DD, bfp, nullptr, hbuf, MC, D_, D_);
  gemm_ffn_kernel<<<dim3(D_ / 64, MC / 64), 256, 0, stream>>>(
      hbuf, wb + 5 * DD, wb + 6 * DD, bw, bv, x3, beta, out);
}

// Round 13
// 203.958 us; speedup vs baseline: 1.0592x; 1.0592x over previous
//
#include <hip/hip_runtime.h>
#include <math.h>

#define B_ 2
#define C_ 1024
#define D_ 1024
#define H_ 16
#define DH_ 64
#define EPSF 1e-8f

typedef __bf16 bf16;
typedef __attribute__((ext_vector_type(4))) __bf16 bf16x4;
typedef __attribute__((ext_vector_type(8))) __bf16 bf16x8;
typedef __attribute__((ext_vector_type(4))) float f32x4;

__device__ inline f32x4 mfma16(bf16x8 a, bf16x8 b, f32x4 c) {
  return __builtin_amdgcn_mfma_f32_16x16x32_bf16(a, b, c, 0, 0, 0);
}

__device__ inline void async16(const bf16* g, bf16* l) {
  __builtin_amdgcn_global_load_lds((const __attribute__((address_space(1))) void*)g,
                                   (__attribute__((address_space(3))) void*)l, 16, 0, 0);
}

// Raw barrier + counted vmcnt (T4).
#define S_BARRIER() asm volatile("s_barrier" ::: "memory")
#define S_VMCNT(N) asm volatile("s_waitcnt vmcnt(" #N ")" ::: "memory")

// theta for rope pair index i (reference uses (i-1)): 10000^(-2(i-1)/64)
__device__ inline float rope_theta(float i) {
  return exp2f(-13.287712379549449f * (2.0f * (i - 1.0f) * (1.0f / 64.0f)));
}

// ---------------- fused: weight cvt (segs 0..6) + RMSNorm fp32->bf16 (blocks 7168+) ----------------
__global__ __launch_bounds__(256) void cvt_rms_kernel(const float* __restrict__ wqkv,
                                                      const float* __restrict__ wout,
                                                      const float* __restrict__ wf,
                                                      const float* __restrict__ www,
                                                      const float* __restrict__ wv,
                                                      bf16* __restrict__ wdst,
                                                      const float* __restrict__ x,
                                                      const float* __restrict__ rw,
                                                      const float* __restrict__ rb,
                                                      bf16* __restrict__ xout) {
  __shared__ float red[4];
  int t = threadIdx.x;
  if (blockIdx.x < 7 * 1024) {
    int seg = blockIdx.x >> 10;
    int local = (blockIdx.x & 1023) * 1024 + t * 4;
    const float* src = seg < 3 ? wqkv + (size_t)seg * (D_ * D_)
                     : seg == 3 ? wout : seg == 4 ? wf : seg == 5 ? www : wv;
    float4 v = *(const float4*)(src + local);
    bf16x4 o;
    o[0] = (bf16)v.x; o[1] = (bf16)v.y; o[2] = (bf16)v.z; o[3] = (bf16)v.w;
    *(bf16x4*)(wdst + (size_t)seg * (D_ * D_) + local) = o;
    return;
  }
  int row = blockIdx.x - 7 * 1024;
  int c = row & (C_ - 1);
  float4 xv = *(const float4*)(x + (size_t)row * D_ + t * 4);
  float ss = xv.x * xv.x + xv.y * xv.y + xv.z * xv.z + xv.w * xv.w;
#pragma unroll
  for (int m = 1; m < 64; m <<= 1) ss += __shfl_xor(ss, m, 64);
  if ((t & 63) == 0) red[t >> 6] = ss;
  __syncthreads();
  float tot = red[0] + red[1] + red[2] + red[3];
  float inv = rsqrtf(tot * (1.0f / D_) + EPSF);
  float4 wv4 = *(const float4*)(rw + (size_t)c * D_ + t * 4);
  float4 bv4 = *(const float4*)(rb + (size_t)c * D_ + t * 4);
  bf16x4 ov;
  ov[0] = (bf16)(wv4.x * (xv.x * inv) + bv4.x);
  ov[1] = (bf16)(wv4.y * (xv.y * inv) + bv4.y);
  ov[2] = (bf16)(wv4.z * (xv.z * inv) + bv4.z);
  ov[3] = (bf16)(wv4.w * (xv.w * inv) + bv4.w);
  *(bf16x4*)(xout + (size_t)row * D_ + t * 4) = ov;
}

// ---------------- RMSNorm (bf16 in, bf16 out) ----------------
__global__ __launch_bounds__(256) void rmsnorm_bf16_kernel(const bf16* __restrict__ x,
                                                           const float* __restrict__ w,
                                                           const float* __restrict__ b,
                                                           bf16* __restrict__ out) {
  int row = blockIdx.x;
  int c = row & (C_ - 1);
  int t = threadIdx.x;
  bf16x4 xv = *(const bf16x4*)(x + (size_t)row * D_ + t * 4);
  float f0 = (float)xv[0], f1 = (float)xv[1], f2 = (float)xv[2], f3 = (float)xv[3];
  float ss = f0 * f0 + f1 * f1 + f2 * f2 + f3 * f3;
#pragma unroll
  for (int m = 1; m < 64; m <<= 1) ss += __shfl_xor(ss, m, 64);
  __shared__ float red[4];
  if ((t & 63) == 0) red[t >> 6] = ss;
  __syncthreads();
  float tot = red[0] + red[1] + red[2] + red[3];
  float inv = rsqrtf(tot * (1.0f / D_) + EPSF);
  float4 wv = *(const float4*)(w + (size_t)c * D_ + t * 4);
  float4 bv = *(const float4*)(b + (size_t)c * D_ + t * 4);
  bf16x4 ov;
  ov[0] = (bf16)(wv.x * (f0 * inv) + bv.x);
  ov[1] = (bf16)(wv.y * (f1 * inv) + bv.y);
  ov[2] = (bf16)(wv.z * (f2 * inv) + bv.z);
  ov[3] = (bf16)(wv.w * (f3 * inv) + bv.w);
  *(bf16x4*)(out + (size_t)row * D_ + t * 4) = ov;
}

// ---------------- generic GEMM: BK=64 <64,64>, dbuf counted-vmcnt (r9 exact) ----------------
template <int BMt, int BNt>
__global__ __launch_bounds__(256) void gemm_lds(const bf16* __restrict__ A,
                                                const bf16* __restrict__ W,
                                                const float* __restrict__ bias,
                                                const bf16* __restrict__ R,
                                                bf16* __restrict__ Cout,
                                                int M, int N, int K) {
  constexpr int BK = 64;
  constexpr int MT = BMt / 32;
  constexpr int NT = BNt / 32;
  __shared__ bf16 sa[2][BMt * BK];
  __shared__ bf16 sb[2][BNt * BK];
  int t = threadIdx.x, l = t & 63, w = t >> 6;
  int m0 = blockIdx.y * BMt;
  int n0 = blockIdx.x * BNt;
  int wm = (w >> 1) * (BMt / 2), wn = (w & 1) * (BNt / 2);
  int lm = l & 15, lq = l >> 4;
  int swz = lm & 7;
  f32x4 acc[MT][NT] = {};

  auto stage = [&](int buf, int k0) {
#pragma unroll
    for (int p = 0; p < BMt / 32; ++p) {
      int lin = p * 256 + t;
      int r = lin >> 3, cc = (lin & 7) ^ (r & 7);
      async16(A + (size_t)(m0 + r) * K + k0 + cc * 8, &sa[buf][lin * 8]);
    }
#pragma unroll
    for (int p = 0; p < BNt / 32; ++p) {
      int lin = p * 256 + t;
      int r = lin >> 3, cc = (lin & 7) ^ (r & 7);
      async16(W + (size_t)(n0 + r) * K + k0 + cc * 8, &sb[buf][lin * 8]);
    }
  };  // 4 vmem per wave for <64,64>

  int NKi = K / BK;
  stage(0, 0);
  int cur = 0;
  for (int i = 0; i < NKi; ++i) {
    if (i + 1 < NKi) {
      stage(cur ^ 1, (i + 1) * BK);
      S_VMCNT(4);
    } else {
      S_VMCNT(0);
    }
    S_BARRIER();
    bf16x8 af[MT][2], bfr[NT][2];
#pragma unroll
    for (int mt = 0; mt < MT; ++mt) {
      const bf16* base = &sa[cur][0] + (wm + mt * 16 + lm) * BK;
      af[mt][0] = *(const bf16x8*)(base + ((lq ^ swz) << 3));
      af[mt][1] = *(const bf16x8*)(base + (((4 | lq) ^ swz) << 3));
    }
#pragma unroll
    for (int nt = 0; nt < NT; ++nt) {
      const bf16* base = &sb[cur][0] + (wn + nt * 16 + lm) * BK;
      bfr[nt][0] = *(const bf16x8*)(base + ((lq ^ swz) << 3));
      bfr[nt][1] = *(const bf16x8*)(base + (((4 | lq) ^ swz) << 3));
    }
#pragma unroll
    for (int mt = 0; mt < MT; ++mt)
#pragma unroll
      for (int nt = 0; nt < NT; ++nt) {
        acc[mt][nt] = mfma16(af[mt][0], bfr[nt][0], acc[mt][nt]);
        acc[mt][nt] = mfma16(af[mt][1], bfr[nt][1], acc[mt][nt]);
      }
    S_BARRIER();
    cur ^= 1;
  }
#pragma unroll
  for (int mt = 0; mt < MT; ++mt)
#pragma unroll
    for (int nt = 0; nt < NT; ++nt) {
      int col = n0 + wn + nt * 16 + lm;
      float bb = bias ? bias[col] : 0.0f;
#pragma unroll
      for (int r = 0; r < 4; ++r) {
        int row = m0 + wm + mt * 16 + lq * 4 + r;
        float v = acc[mt][nt][r] + bb;
        if (R) v += (float)R[(size_t)row * N + col];
        Cout[(size_t)row * N + col] = (bf16)v;
      }
    }
}

// ---------------- QKV GEMM <128,64> BK=64, dbuf counted-vmcnt; V-transpose epilogue (r9 exact) ----------------
__global__ __launch_bounds__(256) void gemm_qkv_kernel(const bf16* __restrict__ A,
                                                       const bf16* __restrict__ W,
                                                       bf16* __restrict__ qkv,
                                                       bf16* __restrict__ vt) {
  constexpr int BK = 64;
  constexpr int BMt = 128, BNt = 64, MT = 4, NT = 2;
  const int N = 3 * D_, K = D_;
  __shared__ bf16 sa[2][BMt * BK];
  __shared__ bf16 sb[2][BNt * BK];
  int t = threadIdx.x, l = t & 63, w = t >> 6;
  int m0 = blockIdx.y * BMt;
  int n0 = blockIdx.x * BNt;
  int wm = (w >> 1) * 64, wn = (w & 1) * 32;
  int lm = l & 15, lq = l >> 4;
  int swz = lm & 7;
  f32x4 acc[MT][NT] = {};

  auto stage = [&](int buf, int k0) {
#pragma unroll
    for (int p = 0; p < 4; ++p) {
      int lin = p * 256 + t;
      int r = lin >> 3, cc = (lin & 7) ^ (r & 7);
      async16(A + (size_t)(m0 + r) * K + k0 + cc * 8, &sa[buf][lin * 8]);
    }
#pragma unroll
    for (int p = 0; p < 2; ++p) {
      int lin = p * 256 + t;
      int r = lin >> 3, cc = (lin & 7) ^ (r & 7);
      async16(W + (size_t)(n0 + r) * K + k0 + cc * 8, &sb[buf][lin * 8]);
    }
  };  // 6 vmem instructions per wave

  int NKi = K / BK;
  stage(0, 0);
  int cur = 0;
  for (int i = 0; i < NKi; ++i) {
    if (i + 1 < NKi) {
      stage(cur ^ 1, (i + 1) * BK);
      S_VMCNT(6);
    } else {
      S_VMCNT(0);
    }
    S_BARRIER();
    bf16x8 af[MT][2], bfr[NT][2];
#pragma unroll
    for (int mt = 0; mt < MT; ++mt) {
      const bf16* base = &sa[cur][0] + (wm + mt * 16 + lm) * BK;
      af[mt][0] = *(const bf16x8*)(base + ((lq ^ swz) << 3));
      af[mt][1] = *(const bf16x8*)(base + (((4 | lq) ^ swz) << 3));
    }
#pragma unroll
    for (int nt = 0; nt < NT; ++nt) {
      const bf16* base = &sb[cur][0] + (wn + nt * 16 + lm) * BK;
      bfr[nt][0] = *(const bf16x8*)(base + ((lq ^ swz) << 3));
      bfr[nt][1] = *(const bf16x8*)(base + (((4 | lq) ^ swz) << 3));
    }
#pragma unroll
    for (int mt = 0; mt < MT; ++mt)
#pragma unroll
      for (int nt = 0; nt < NT; ++nt) {
        acc[mt][nt] = mfma16(af[mt][0], bfr[nt][0], acc[mt][nt]);
        acc[mt][nt] = mfma16(af[mt][1], bfr[nt][1], acc[mt][nt]);
      }
    S_BARRIER();
    cur ^= 1;
  }
  if (n0 < 2 * D_) {
#pragma unroll
    for (int mt = 0; mt < MT; ++mt)
#pragma unroll
      for (int nt = 0; nt < NT; ++nt) {
        int col = n0 + wn + nt * 16 + lm;
#pragma unroll
        for (int r = 0; r < 4; ++r) {
          int row = m0 + wm + mt * 16 + lq * 4 + r;
          qkv[(size_t)row * N + col] = (bf16)acc[mt][nt][r];
        }
      }
  } else {
    bf16* tv = &sa[0][0];  // 64*136 = 8704 elems; all compute done (final barrier passed)
#pragma unroll
    for (int mt = 0; mt < MT; ++mt)
#pragma unroll
      for (int nt = 0; nt < NT; ++nt) {
        int dh = wn + nt * 16 + lm;
#pragma unroll
        for (int r = 0; r < 4; ++r)
          tv[dh * 136 + wm + mt * 16 + lq * 4 + r] = (bf16)acc[mt][nt][r];
      }
    __syncthreads();
    int h = (n0 - 2 * D_) >> 6;
    int bb = m0 >> 10;
    int mloc = m0 & 1023;
    size_t vbase = (size_t)((bb * H_ + h) * DH_) * C_;
#pragma unroll
    for (int p = 0; p < 4; ++p) {
      int lin = p * 256 + t;
      int dh = lin >> 4;
      int mm = (lin & 15) * 8;
      *(int4*)(vt + vbase + (size_t)dh * C_ + mloc + mm) = *(int4*)(tv + dh * 136 + mm);
    }
  }
}

// ---------------- Fused FFN tail: BK=64, dbuf counted-vmcnt (r9 exact) ----------------
__global__ __launch_bounds__(256) void gemm_ffn_kernel(const bf16* __restrict__ A,
                                                       const bf16* __restrict__ Ww,
                                                       const bf16* __restrict__ Wv,
                                                       const float* __restrict__ bw,
                                                       const float* __restrict__ bv,
                                                       const bf16* __restrict__ x3,
                                                       const float* __restrict__ beta_p,
                                                       float* __restrict__ out) {
  constexpr int BK = 64;
  __shared__ bf16 sa[2][64 * BK];
  __shared__ bf16 sb1[2][64 * BK];
  __shared__ bf16 sb2[2][64 * BK];
  int t = threadIdx.x, l = t & 63, w = t >> 6;
  int m0 = blockIdx.y * 64, n0 = blockIdx.x * 64;
  int wm = (w >> 1) * 32, wn = (w & 1) * 32;
  int lm = l & 15, lq = l >> 4;
  int swz = lm & 7;
  float beta = beta_p[0];
  f32x4 acc1[2][2] = {}, acc2[2][2] = {};

  auto stage = [&](int buf, int k0) {
#pragma unroll
    for (int p = 0; p < 2; ++p) {
      int lin = p * 256 + t;
      int r = lin >> 3, cc = (lin & 7) ^ (r & 7);
      async16(A + (size_t)(m0 + r) * D_ + k0 + cc * 8, &sa[buf][lin * 8]);
      async16(Ww + (size_t)(n0 + r) * D_ + k0 + cc * 8, &sb1[buf][lin * 8]);
      async16(Wv + (size_t)(n0 + r) * D_ + k0 + cc * 8, &sb2[buf][lin * 8]);
    }
  };  // 6 vmem instructions per wave

  int NKi = D_ / BK;
  stage(0, 0);
  int cur = 0;
  for (int i = 0; i < NKi; ++i) {
    if (i + 1 < NKi) {
      stage(cur ^ 1, (i + 1) * BK);
      S_VMCNT(6);
    } else {
      S_VMCNT(0);
    }
    S_BARRIER();
    bf16x8 af[2][2], b1f[2][2], b2f[2][2];
#pragma unroll
    for (int mt = 0; mt < 2; ++mt) {
      const bf16* base = &sa[cur][0] + (wm + mt * 16 + lm) * BK;
      af[mt][0] = *(const bf16x8*)(base + ((lq ^ swz) << 3));
      af[mt][1] = *(const bf16x8*)(base + (((4 | lq) ^ swz) << 3));
    }
#pragma unroll
    for (int nt = 0; nt < 2; ++nt) {
      const bf16* base1 = &sb1[cur][0] + (wn + nt * 16 + lm) * BK;
      const bf16* base2 = &sb2[cur][0] + (wn + nt * 16 + lm) * BK;
      b1f[nt][0] = *(const bf16x8*)(base1 + ((lq ^ swz) << 3));
      b1f[nt][1] = *(const bf16x8*)(base1 + (((4 | lq) ^ swz) << 3));
      b2f[nt][0] = *(const bf16x8*)(base2 + ((lq ^ swz) << 3));
      b2f[nt][1] = *(const bf16x8*)(base2 + (((4 | lq) ^ swz) << 3));
    }
#pragma unroll
    for (int mt = 0; mt < 2; ++mt)
#pragma unroll
      for (int nt = 0; nt < 2; ++nt) {
        acc1[mt][nt] = mfma16(af[mt][0], b1f[nt][0], acc1[mt][nt]);
        acc1[mt][nt] = mfma16(af[mt][1], b1f[nt][1], acc1[mt][nt]);
        acc2[mt][nt] = mfma16(af[mt][0], b2f[nt][0], acc2[mt][nt]);
        acc2[mt][nt] = mfma16(af[mt][1], b2f[nt][1], acc2[mt][nt]);
      }
    S_BARRIER();
    cur ^= 1;
  }
#pragma unroll
  for (int mt = 0; mt < 2; ++mt)
#pragma unroll
    for (int nt = 0; nt < 2; ++nt) {
      int col = n0 + wn + nt * 16 + lm;
      float bbw = bw[col], bbv = bv[col];
#pragma unroll
      for (int r = 0; r < 4; ++r) {
        int row = m0 + wm + mt * 16 + lq * 4 + r;
        float z = acc1[mt][nt][r] + bbw;
        float g = acc2[mt][nt][r] + bbv;
        float sw_ = z / (1.0f + __expf(-beta * z));
        out[(size_t)row * D_ + col] = (float)x3[(size_t)row * D_ + col] + sw_ * g;
      }
    }
}

// ---------------- Fused attention v11: r9's v10 + T5 s_setprio around MFMA clusters ----------------
// 2 independent blocks/CU (no inter-block coupling) = the m191 regime where setprio
// lets the CU scheduler favor the MFMA wave over the other block's load/VALU waves.
__global__ __launch_bounds__(256) void attn_kernel(const bf16* __restrict__ qkv,
                                                   const bf16* __restrict__ vt,
                                                   bf16* __restrict__ y) {
  __shared__ bf16 sk[2][64 * 72];
  __shared__ bf16 skr[2][64 * 72];
  __shared__ bf16 sv[2][64 * 72];
  __shared__ bf16 pl[4][16 * 72];
  int t = threadIdx.x, l = t & 63, w = t >> 6;
  int blk = blockIdx.x;  // 512
  int idx = blk & 255;
  int it = (blk < 256) ? (idx >> 5) : (15 - (idx >> 5));  // balanced (k,15-k) CU pairs
  int r5 = idx & 31;
  int b = r5 >> 4;
  int h = r5 & 15;
  int i_base = it * 64 + w * 16;
  int lm = l & 15, lq = l >> 4;
  const float scale = 0.125f;

  size_t hq = (size_t)h * DH_;
  size_t qrow = (size_t)(b * C_ + i_base + lm) * (3 * D_) + hq;
  bf16x8 qp[2], qrf[2];
  float cq = (float)(i_base + lm);
#pragma unroll
  for (int kk = 0; kk < 2; ++kk) {
    qp[kk] = *(const bf16x8*)(qkv + qrow + kk * 32 + lq * 8);
#pragma unroll
    for (int j = 0; j < 4; ++j) {
      float ip = (float)(kk * 16 + lq * 4 + j);
      float ang = cq * rope_theta(ip);
      float sv_, cv_;
      __sincosf(ang, &sv_, &cv_);
      float qe = (float)qp[kk][2 * j], qo = (float)qp[kk][2 * j + 1];
      qrf[kk][2 * j] = (bf16)(qe * cv_ + qo * sv_);
      qrf[kk][2 * j + 1] = (bf16)(qo * cv_ - qe * sv_);
    }
  }

  float den[4] = {0.f, 0.f, 0.f, 0.f};
  f32x4 yacc[4] = {};
  int i_max = i_base + 15;
  size_t kbase = (size_t)(b * C_) * (3 * D_) + D_ + hq;
  size_t vtbase = (size_t)((b * H_ + h) * DH_) * C_;
  int sr = t >> 3;
  int sc = (t & 7) * 8;
  float th0 = rope_theta((float)((sc >> 1) + 0));
  float th1 = rope_theta((float)((sc >> 1) + 1));
  float th2 = rope_theta((float)((sc >> 1) + 2));
  float th3 = rope_theta((float)((sc >> 1) + 3));

  int4 pk0, pk1, pv0, pv1, rk0, rk1;
#define FETCH_TILE(J0)                                                          \
  pk0 = *(const int4*)(qkv + kbase + (size_t)((J0) + sr) * (3 * D_) + sc);      \
  pk1 = *(const int4*)(qkv + kbase + (size_t)((J0) + 32 + sr) * (3 * D_) + sc); \
  pv0 = *(const int4*)(vt + vtbase + (size_t)sr * C_ + (J0) + sc);              \
  pv1 = *(const int4*)(vt + vtbase + (size_t)(32 + sr) * C_ + (J0) + sc);

#define ROTP(KV, RV, P)                                       \
  {                                                           \
    float e = (float)KV[2 * P], o = (float)KV[2 * P + 1];     \
    RV[2 * P] = (bf16)(e * c_ + o * s_);                      \
    RV[2 * P + 1] = (bf16)(o * c_ - e * s_);                  \
  }
#define ROTATE(J0)                                            \
  {                                                           \
    bf16x8 k0 = *(bf16x8*)&pk0, k1 = *(bf16x8*)&pk1;          \
    bf16x8 r0, r1;                                            \
    float jA = (float)((J0) + sr), jB = (float)((J0) + 32 + sr); \
    float s_, c_;                                             \
    __sincosf(jA * th0, &s_, &c_); ROTP(k0, r0, 0)            \
    __sincosf(jA * th1, &s_, &c_); ROTP(k0, r0, 1)            \
    __sincosf(jA * th2, &s_, &c_); ROTP(k0, r0, 2)            \
    __sincosf(jA * th3, &s_, &c_); ROTP(k0, r0, 3)            \
    __sincosf(jB * th0, &s_, &c_); ROTP(k1, r1, 0)            \
    __sincosf(jB * th1, &s_, &c_); ROTP(k1, r1, 1)            \
    __sincosf(jB * th2, &s_, &c_); ROTP(k1, r1, 2)            \
    __sincosf(jB * th3, &s_, &c_); ROTP(k1, r1, 3)            \
    rk0 = *(int4*)&r0;                                        \
    rk1 = *(int4*)&r1;                                        \
  }

  FETCH_TILE(0)
  ROTATE(0)

  for (int j0 = 0; j0 < C_; j0 += 64) {
    int bu = (j0 >> 6) & 1;
    *(int4*)(&sk[bu][0] + sr * 72 + sc) = pk0;
    *(int4*)(&sk[bu][0] + (32 + sr) * 72 + sc) = pk1;
    *(int4*)(&skr[bu][0] + sr * 72 + sc) = rk0;
    *(int4*)(&skr[bu][0] + (32 + sr) * 72 + sc) = rk1;
    *(int4*)(&sv[bu][0] + sr * 72 + sc) = pv0;
    *(int4*)(&sv[bu][0] + (32 + sr) * 72 + sc) = pv1;
    __syncthreads();  // single barrier per tile: publishes buf[bu]
    if (j0 + 64 < C_) {
      FETCH_TILE(j0 + 64)
    }
    // denominator: unrotated q.k over all j (T5: elevate MFMA cluster)
    __builtin_amdgcn_s_setprio(1);
#pragma unroll
    for (int js = 0; js < 64; js += 16) {
      bf16x8 kf0 = *(const bf16x8*)(&sk[bu][0] + (js + lm) * 72 + lq * 8);
      bf16x8 kf1 = *(const bf16x8*)(&sk[bu][0] + (js + lm) * 72 + 32 + lq * 8);
      f32x4 s = {0.f, 0.f, 0.f, 0.f};
      s = mfma16(qp[0], kf0, s);
      s = mfma16(qp[1], kf1, s);
#pragma unroll
      for (int r = 0; r < 4; ++r) den[r] += __expf(s[r] * scale);
    }
    __builtin_amdgcn_s_setprio(0);
    // numerator + PV: causal tiles only (wave-uniform guard)
    if (j0 <= i_max) {
      __builtin_amdgcn_s_setprio(1);
#pragma unroll
      for (int js = 0; js < 64; js += 16) {
        bf16x8 kf0 = *(const bf16x8*)(&skr[bu][0] + (js + lm) * 72 + lq * 8);
        bf16x8 kf1 = *(const bf16x8*)(&skr[bu][0] + (js + lm) * 72 + 32 + lq * 8);
        f32x4 s = {0.f, 0.f, 0.f, 0.f};
        s = mfma16(qrf[0], kf0, s);
        s = mfma16(qrf[1], kf1, s);
#pragma unroll
        for (int r = 0; r < 4; ++r) {
          int jg = j0 + js + lm;
          int ig = i_base + lq * 4 + r;
          float p = (jg <= ig) ? __expf(s[r] * scale) : 0.0f;
          pl[w][(lq * 4 + r) * 72 + js + lm] = (bf16)p;
        }
      }
      __builtin_amdgcn_wave_barrier();
      bf16x8 pf0 = *(const bf16x8*)(pl[w] + lm * 72 + lq * 8);
      bf16x8 pf1 = *(const bf16x8*)(pl[w] + lm * 72 + 32 + lq * 8);
#pragma unroll
      for (int tt = 0; tt < 4; ++tt) {
        bf16x8 vf0 = *(const bf16x8*)(&sv[bu][0] + (tt * 16 + lm) * 72 + lq * 8);
        bf16x8 vf1 = *(const bf16x8*)(&sv[bu][0] + (tt * 16 + lm) * 72 + 32 + lq * 8);
        yacc[tt] = mfma16(pf0, vf0, mfma16(pf1, vf1, yacc[tt]));
      }
      __builtin_amdgcn_wave_barrier();
      __builtin_amdgcn_s_setprio(0);
    }
    // rotate NEXT tile's K (loads landed during compute; pure VALU, off the serial path)
    if (j0 + 64 < C_) {
      ROTATE(j0 + 64)
    }
  }
#undef FETCH_TILE
#undef ROTATE
#undef ROTP
  // normalize in-register and write y directly (no combine pass)
  float inv[4];
#pragma unroll
  for (int r = 0; r < 4; ++r) {
    float d = den[r];
    d += __shfl_xor(d, 1, 64);
    d += __shfl_xor(d, 2, 64);
    d += __shfl_xor(d, 4, 64);
    d += __shfl_xor(d, 8, 64);
    inv[r] = 1.0f / d;
  }
#pragma unroll
  for (int tt = 0; tt < 4; ++tt)
#pragma unroll
    for (int r = 0; r < 4; ++r) {
      int ig = i_base + lq * 4 + r;
      y[(size_t)(b * C_ + ig) * D_ + hq + tt * 16 + lm] = (bf16)(yacc[tt][r] * inv[r]);
    }
}

extern "C" void kernel_launch(void* const* d_in, const int* in_sizes, int n_in,
                              void* d_out, int out_size, void* d_ws, size_t ws_size,
                              hipStream_t stream) {
  const float* x = (const float*)d_in[0];
  const float* rms_w = (const float*)d_in[1];
  const float* rms_b = (const float*)d_in[2];
  const float* Wqkv = (const float*)d_in[3];
  const float* Wout = (const float*)d_in[4];
  const float* bout = (const float*)d_in[5];
  const float* Wf = (const float*)d_in[6];
  const float* bfp = (const float*)d_in[7];
  const float* Ww = (const float*)d_in[8];
  const float* bw = (const float*)d_in[9];
  const float* Wv = (const float*)d_in[10];
  const float* bv = (const float*)d_in[11];
  const float* beta = (const float*)d_in[12];
  float* out = (float*)d_out;

  bf16* ws = (bf16*)d_ws;
  const size_t DD = (size_t)D_ * D_;
  const size_t MC = (size_t)B_ * C_;
  bf16* wb = ws;            // 7DD: Wqkv(3), Wout, Wf, Ww, Wv
  bf16* x1 = ws + 7 * DD;
  bf16* qkv = ws + 9 * DD;
  bf16* vt = ws + 15 * DD;
  bf16* x2 = ws + 17 * DD;
  bf16* x3 = ws + 19 * DD;
  bf16* hbuf = ws + 21 * DD;
  bf16* y = (bf16*)d_out;   // bf16 y inside fp32 d_out; consumed before final write

  cvt_rms_kernel<<<7 * 1024 + MC, 256, 0, stream>>>(Wqkv, Wout, Wf, Ww, Wv, wb, x, rms_w,
                                                    rms_b, x1);
  gemm_qkv_kernel<<<dim3(3 * D_ / 64, MC / 128), 256, 0, stream>>>(x1, wb, qkv, vt);
  attn_kernel<<<B_ * H_ * 16, 256, 0, stream>>>(qkv, vt, y);
  gemm_lds<64, 64><<<dim3(D_ / 64, MC / 64), 256, 0, stream>>>(
      y, wb + 3 * DD, bout, x1, x2, MC, D_, D_);
  rmsnorm_bf16_kernel<<<MC, 256, 0, stream>>>(x2, rms_w, rms_b, x3);
  gemm_lds<64, 64><<<dim3(D_ / 64, MC / 64), 256, 0, stream>>>(
      x3, wb + 4 * DD, bfp, nullptr, hbuf, MC, D_, D_);
  gemm_ffn_kernel<<<dim3(D_ / 64, MC / 64), 256, 0, stream>>>(
      hbuf, wb + 5 * DD, wb + 6 * DD, bw, bv, x3, beta, out);
}

// Round 14
// 202.644 us; speedup vs baseline: 1.0661x; 1.0065x over previous
//
#include <hip/hip_runtime.h>
#include <math.h>

#define B_ 2
#define C_ 1024
#define D_ 1024
#define H_ 16
#define DH_ 64
#define EPSF 1e-8f

typedef __bf16 bf16;
typedef __attribute__((ext_vector_type(4))) __bf16 bf16x4;
typedef __attribute__((ext_vector_type(8))) __bf16 bf16x8;
typedef __attribute__((ext_vector_type(4))) float f32x4;

__device__ inline f32x4 mfma16(bf16x8 a, bf16x8 b, f32x4 c) {
  return __builtin_amdgcn_mfma_f32_16x16x32_bf16(a, b, c, 0, 0, 0);
}

__device__ inline void async16(const bf16* g, bf16* l) {
  __builtin_amdgcn_global_load_lds((const __attribute__((address_space(1))) void*)g,
                                   (__attribute__((address_space(3))) void*)l, 16, 0, 0);
}

// Raw barrier + counted vmcnt (T4).
#define S_BARRIER() asm volatile("s_barrier" ::: "memory")
#define S_VMCNT(N) asm volatile("s_waitcnt vmcnt(" #N ")" ::: "memory")

// theta for rope pair index i (reference uses (i-1)): 10000^(-2(i-1)/64)
__device__ inline float rope_theta(float i) {
  return exp2f(-13.287712379549449f * (2.0f * (i - 1.0f) * (1.0f / 64.0f)));
}

// ---------------- fused: weight cvt (segs 0..6) + RMSNorm fp32->bf16 (blocks 7168+) ----------------
__global__ __launch_bounds__(256) void cvt_rms_kernel(const float* __restrict__ wqkv,
                                                      const float* __restrict__ wout,
                                                      const float* __restrict__ wf,
                                                      const float* __restrict__ www,
                                                      const float* __restrict__ wv,
                                                      bf16* __restrict__ wdst,
                                                      const float* __restrict__ x,
                                                      const float* __restrict__ rw,
                                                      const float* __restrict__ rb,
                                                      bf16* __restrict__ xout) {
  __shared__ float red[4];
  int t = threadIdx.x;
  if (blockIdx.x < 7 * 1024) {
    int seg = blockIdx.x >> 10;
    int local = (blockIdx.x & 1023) * 1024 + t * 4;
    const float* src = seg < 3 ? wqkv + (size_t)seg * (D_ * D_)
                     : seg == 3 ? wout : seg == 4 ? wf : seg == 5 ? www : wv;
    float4 v = *(const float4*)(src + local);
    bf16x4 o;
    o[0] = (bf16)v.x; o[1] = (bf16)v.y; o[2] = (bf16)v.z; o[3] = (bf16)v.w;
    *(bf16x4*)(wdst + (size_t)seg * (D_ * D_) + local) = o;
    return;
  }
  int row = blockIdx.x - 7 * 1024;
  int c = row & (C_ - 1);
  float4 xv = *(const float4*)(x + (size_t)row * D_ + t * 4);
  float ss = xv.x * xv.x + xv.y * xv.y + xv.z * xv.z + xv.w * xv.w;
#pragma unroll
  for (int m = 1; m < 64; m <<= 1) ss += __shfl_xor(ss, m, 64);
  if ((t & 63) == 0) red[t >> 6] = ss;
  __syncthreads();
  float tot = red[0] + red[1] + red[2] + red[3];
  float inv = rsqrtf(tot * (1.0f / D_) + EPSF);
  float4 wv4 = *(const float4*)(rw + (size_t)c * D_ + t * 4);
  float4 bv4 = *(const float4*)(rb + (size_t)c * D_ + t * 4);
  bf16x4 ov;
  ov[0] = (bf16)(wv4.x * (xv.x * inv) + bv4.x);
  ov[1] = (bf16)(wv4.y * (xv.y * inv) + bv4.y);
  ov[2] = (bf16)(wv4.z * (xv.z * inv) + bv4.z);
  ov[3] = (bf16)(wv4.w * (xv.w * inv) + bv4.w);
  *(bf16x4*)(xout + (size_t)row * D_ + t * 4) = ov;
}

// ---------------- RMSNorm (bf16 in, bf16 out) ----------------
__global__ __launch_bounds__(256) void rmsnorm_bf16_kernel(const bf16* __restrict__ x,
                                                           const float* __restrict__ w,
                                                           const float* __restrict__ b,
                                                           bf16* __restrict__ out) {
  int row = blockIdx.x;
  int c = row & (C_ - 1);
  int t = threadIdx.x;
  bf16x4 xv = *(const bf16x4*)(x + (size_t)row * D_ + t * 4);
  float f0 = (float)xv[0], f1 = (float)xv[1], f2 = (float)xv[2], f3 = (float)xv[3];
  float ss = f0 * f0 + f1 * f1 + f2 * f2 + f3 * f3;
#pragma unroll
  for (int m = 1; m < 64; m <<= 1) ss += __shfl_xor(ss, m, 64);
  __shared__ float red[4];
  if ((t & 63) == 0) red[t >> 6] = ss;
  __syncthreads();
  float tot = red[0] + red[1] + red[2] + red[3];
  float inv = rsqrtf(tot * (1.0f / D_) + EPSF);
  float4 wv = *(const float4*)(w + (size_t)c * D_ + t * 4);
  float4 bv = *(const float4*)(b + (size_t)c * D_ + t * 4);
  bf16x4 ov;
  ov[0] = (bf16)(wv.x * (f0 * inv) + bv.x);
  ov[1] = (bf16)(wv.y * (f1 * inv) + bv.y);
  ov[2] = (bf16)(wv.z * (f2 * inv) + bv.z);
  ov[3] = (bf16)(wv.w * (f3 * inv) + bv.w);
  *(bf16x4*)(out + (size_t)row * D_ + t * 4) = ov;
}

// ---------------- generic GEMM: BK=128, double-buffered, counted-vmcnt pipeline (r7) ----------------
template <int BMt, int BNt>
__global__ __launch_bounds__(256) void gemm_lds(const bf16* __restrict__ A,
                                                const bf16* __restrict__ W,
                                                const float* __restrict__ bias,
                                                const bf16* __restrict__ R,
                                                bf16* __restrict__ Cout,
                                                int M, int N, int K) {
  constexpr int BK = 128;
  constexpr int MT = BMt / 32;
  constexpr int NT = BNt / 32;
  __shared__ bf16 sa[2][BMt * BK];
  __shared__ bf16 sb[2][BNt * BK];
  int t = threadIdx.x, l = t & 63, w = t >> 6;
  int m0 = blockIdx.y * BMt;
  int n0 = blockIdx.x * BNt;
  int wm = (w >> 1) * (BMt / 2), wn = (w & 1) * (BNt / 2);
  int lm = l & 15, lq = l >> 4;
  int swz = lm & 7;
  f32x4 acc[MT][NT] = {};

  auto stage = [&](int buf, int k0) {
#pragma unroll
    for (int p = 0; p < BMt / 16; ++p) {
      int lin = p * 256 + t;
      int r = lin >> 4, cc = (lin & 15) ^ (r & 7);
      async16(A + (size_t)(m0 + r) * K + k0 + cc * 8, &sa[buf][lin * 8]);
    }
#pragma unroll
    for (int p = 0; p < BNt / 16; ++p) {
      int lin = p * 256 + t;
      int r = lin >> 4, cc = (lin & 15) ^ (r & 7);
      async16(W + (size_t)(n0 + r) * K + k0 + cc * 8, &sb[buf][lin * 8]);
    }
  };  // 8 vmem instructions per wave

  int NKi = K / BK;
  stage(0, 0);
  int cur = 0;
  for (int i = 0; i < NKi; ++i) {
    if (i + 1 < NKi) {
      stage(cur ^ 1, (i + 1) * BK);
      S_VMCNT(8);
    } else {
      S_VMCNT(0);
    }
    S_BARRIER();
#pragma unroll
    for (int hh = 0; hh < 4; ++hh) {
      bf16x8 af[MT], bfr[NT];
#pragma unroll
      for (int mt = 0; mt < MT; ++mt)
        af[mt] = *(const bf16x8*)(&sa[cur][0] + (wm + mt * 16 + lm) * BK +
                                  ((((hh << 2) | lq) ^ swz) << 3));
#pragma unroll
      for (int nt = 0; nt < NT; ++nt)
        bfr[nt] = *(const bf16x8*)(&sb[cur][0] + (wn + nt * 16 + lm) * BK +
                                   ((((hh << 2) | lq) ^ swz) << 3));
#pragma unroll
      for (int mt = 0; mt < MT; ++mt)
#pragma unroll
        for (int nt = 0; nt < NT; ++nt)
          acc[mt][nt] = mfma16(af[mt], bfr[nt], acc[mt][nt]);
    }
    S_BARRIER();
    cur ^= 1;
  }
#pragma unroll
  for (int mt = 0; mt < MT; ++mt)
#pragma unroll
    for (int nt = 0; nt < NT; ++nt) {
      int col = n0 + wn + nt * 16 + lm;
      float bb = bias ? bias[col] : 0.0f;
#pragma unroll
      for (int r = 0; r < 4; ++r) {
        int row = m0 + wm + mt * 16 + lq * 4 + r;
        float v = acc[mt][nt][r] + bb;
        if (R) v += (float)R[(size_t)row * N + col];
        Cout[(size_t)row * N + col] = (bf16)v;
      }
    }
}

// ---------------- QKV GEMM <128,64> BK=64, dbuf counted-vmcnt; V-transpose epilogue (r7) ----------------
__global__ __launch_bounds__(256) void gemm_qkv_kernel(const bf16* __restrict__ A,
                                                       const bf16* __restrict__ W,
                                                       bf16* __restrict__ qkv,
                                                       bf16* __restrict__ vt) {
  constexpr int BK = 64;
  constexpr int BMt = 128, BNt = 64, MT = 4, NT = 2;
  const int N = 3 * D_, K = D_;
  __shared__ bf16 sa[2][BMt * BK];
  __shared__ bf16 sb[2][BNt * BK];
  int t = threadIdx.x, l = t & 63, w = t >> 6;
  int m0 = blockIdx.y * BMt;
  int n0 = blockIdx.x * BNt;
  int wm = (w >> 1) * 64, wn = (w & 1) * 32;
  int lm = l & 15, lq = l >> 4;
  int swz = lm & 7;
  f32x4 acc[MT][NT] = {};

  auto stage = [&](int buf, int k0) {
#pragma unroll
    for (int p = 0; p < 4; ++p) {
      int lin = p * 256 + t;
      int r = lin >> 3, cc = (lin & 7) ^ (r & 7);
      async16(A + (size_t)(m0 + r) * K + k0 + cc * 8, &sa[buf][lin * 8]);
    }
#pragma unroll
    for (int p = 0; p < 2; ++p) {
      int lin = p * 256 + t;
      int r = lin >> 3, cc = (lin & 7) ^ (r & 7);
      async16(W + (size_t)(n0 + r) * K + k0 + cc * 8, &sb[buf][lin * 8]);
    }
  };  // 6 vmem instructions per wave

  int NKi = K / BK;
  stage(0, 0);
  int cur = 0;
  for (int i = 0; i < NKi; ++i) {
    if (i + 1 < NKi) {
      stage(cur ^ 1, (i + 1) * BK);
      S_VMCNT(6);
    } else {
      S_VMCNT(0);
    }
    S_BARRIER();
    bf16x8 af[MT][2], bfr[NT][2];
#pragma unroll
    for (int mt = 0; mt < MT; ++mt) {
      const bf16* base = &sa[cur][0] + (wm + mt * 16 + lm) * BK;
      af[mt][0] = *(const bf16x8*)(base + ((lq ^ swz) << 3));
      af[mt][1] = *(const bf16x8*)(base + (((4 | lq) ^ swz) << 3));
    }
#pragma unroll
    for (int nt = 0; nt < NT; ++nt) {
      const bf16* base = &sb[cur][0] + (wn + nt * 16 + lm) * BK;
      bfr[nt][0] = *(const bf16x8*)(base + ((lq ^ swz) << 3));
      bfr[nt][1] = *(const bf16x8*)(base + (((4 | lq) ^ swz) << 3));
    }
#pragma unroll
    for (int mt = 0; mt < MT; ++mt)
#pragma unroll
      for (int nt = 0; nt < NT; ++nt) {
        acc[mt][nt] = mfma16(af[mt][0], bfr[nt][0], acc[mt][nt]);
        acc[mt][nt] = mfma16(af[mt][1], bfr[nt][1], acc[mt][nt]);
      }
    S_BARRIER();
    cur ^= 1;
  }
  if (n0 < 2 * D_) {
#pragma unroll
    for (int mt = 0; mt < MT; ++mt)
#pragma unroll
      for (int nt = 0; nt < NT; ++nt) {
        int col = n0 + wn + nt * 16 + lm;
#pragma unroll
        for (int r = 0; r < 4; ++r) {
          int row = m0 + wm + mt * 16 + lq * 4 + r;
          qkv[(size_t)row * N + col] = (bf16)acc[mt][nt][r];
        }
      }
  } else {
    bf16* tv = &sa[0][0];  // 64*136 = 8704 elems; all compute done (final barrier passed)
#pragma unroll
    for (int mt = 0; mt < MT; ++mt)
#pragma unroll
      for (int nt = 0; nt < NT; ++nt) {
        int dh = wn + nt * 16 + lm;
#pragma unroll
        for (int r = 0; r < 4; ++r)
          tv[dh * 136 + wm + mt * 16 + lq * 4 + r] = (bf16)acc[mt][nt][r];
      }
    __syncthreads();
    int h = (n0 - 2 * D_) >> 6;
    int bb = m0 >> 10;
    int mloc = m0 & 1023;
    size_t vbase = (size_t)((bb * H_ + h) * DH_) * C_;
#pragma unroll
    for (int p = 0; p < 4; ++p) {
      int lin = p * 256 + t;
      int dh = lin >> 4;
      int mm = (lin & 15) * 8;
      *(int4*)(vt + vbase + (size_t)dh * C_ + mloc + mm) = *(int4*)(tv + dh * 136 + mm);
    }
  }
}

// ---------------- Fused FFN tail: BK=64, dbuf counted-vmcnt (r7) ----------------
__global__ __launch_bounds__(256) void gemm_ffn_kernel(const bf16* __restrict__ A,
                                                       const bf16* __restrict__ Ww,
                                                       const bf16* __restrict__ Wv,
                                                       const float* __restrict__ bw,
                                                       const float* __restrict__ bv,
                                                       const bf16* __restrict__ x3,
                                                       const float* __restrict__ beta_p,
                                                       float* __restrict__ out) {
  constexpr int BK = 64;
  __shared__ bf16 sa[2][64 * BK];
  __shared__ bf16 sb1[2][64 * BK];
  __shared__ bf16 sb2[2][64 * BK];
  int t = threadIdx.x, l = t & 63, w = t >> 6;
  int m0 = blockIdx.y * 64, n0 = blockIdx.x * 64;
  int wm = (w >> 1) * 32, wn = (w & 1) * 32;
  int lm = l & 15, lq = l >> 4;
  int swz = lm & 7;
  float beta = beta_p[0];
  f32x4 acc1[2][2] = {}, acc2[2][2] = {};

  auto stage = [&](int buf, int k0) {
#pragma unroll
    for (int p = 0; p < 2; ++p) {
      int lin = p * 256 + t;
      int r = lin >> 3, cc = (lin & 7) ^ (r & 7);
      async16(A + (size_t)(m0 + r) * D_ + k0 + cc * 8, &sa[buf][lin * 8]);
      async16(Ww + (size_t)(n0 + r) * D_ + k0 + cc * 8, &sb1[buf][lin * 8]);
      async16(Wv + (size_t)(n0 + r) * D_ + k0 + cc * 8, &sb2[buf][lin * 8]);
    }
  };  // 6 vmem instructions per wave

  int NKi = D_ / BK;
  stage(0, 0);
  int cur = 0;
  for (int i = 0; i < NKi; ++i) {
    if (i + 1 < NKi) {
      stage(cur ^ 1, (i + 1) * BK);
      S_VMCNT(6);
    } else {
      S_VMCNT(0);
    }
    S_BARRIER();
    bf16x8 af[2][2], b1f[2][2], b2f[2][2];
#pragma unroll
    for (int mt = 0; mt < 2; ++mt) {
      const bf16* base = &sa[cur][0] + (wm + mt * 16 + lm) * BK;
      af[mt][0] = *(const bf16x8*)(base + ((lq ^ swz) << 3));
      af[mt][1] = *(const bf16x8*)(base + (((4 | lq) ^ swz) << 3));
    }
#pragma unroll
    for (int nt = 0; nt < 2; ++nt) {
      const bf16* base1 = &sb1[cur][0] + (wn + nt * 16 + lm) * BK;
      const bf16* base2 = &sb2[cur][0] + (wn + nt * 16 + lm) * BK;
      b1f[nt][0] = *(const bf16x8*)(base1 + ((lq ^ swz) << 3));
      b1f[nt][1] = *(const bf16x8*)(base1 + (((4 | lq) ^ swz) << 3));
      b2f[nt][0] = *(const bf16x8*)(base2 + ((lq ^ swz) << 3));
      b2f[nt][1] = *(const bf16x8*)(base2 + (((4 | lq) ^ swz) << 3));
    }
#pragma unroll
    for (int mt = 0; mt < 2; ++mt)
#pragma unroll
      for (int nt = 0; nt < 2; ++nt) {
        acc1[mt][nt] = mfma16(af[mt][0], b1f[nt][0], acc1[mt][nt]);
        acc1[mt][nt] = mfma16(af[mt][1], b1f[nt][1], acc1[mt][nt]);
        acc2[mt][nt] = mfma16(af[mt][0], b2f[nt][0], acc2[mt][nt]);
        acc2[mt][nt] = mfma16(af[mt][1], b2f[nt][1], acc2[mt][nt]);
      }
    S_BARRIER();
    cur ^= 1;
  }
#pragma unroll
  for (int mt = 0; mt < 2; ++mt)
#pragma unroll
    for (int nt = 0; nt < 2; ++nt) {
      int col = n0 + wn + nt * 16 + lm;
      float bbw = bw[col], bbv = bv[col];
#pragma unroll
      for (int r = 0; r < 4; ++r) {
        int row = m0 + wm + mt * 16 + lq * 4 + r;
        float z = acc1[mt][nt][r] + bbw;
        float g = acc2[mt][nt][r] + bbv;
        float sw_ = z / (1.0f + __expf(-beta * z));
        out[(size_t)row * D_ + col] = (float)x3[(size_t)row * D_ + col] + sw_ * g;
      }
    }
}

// ---------------- Fused attention v10 (r9 best: dbuf K/Kr/V, one barrier per j-tile) ----------------
// Hazard ledger: iter i stores buf[i&1], sync(i), reads buf[i&1]. Wave A's iter-(i+2)
// store targets buf[i&1]; A passes sync(i+1) first, which requires every wave to have
// finished iter-i reads. One barrier of separation -- race-free.
// LDS 63 KB -> 2 blocks/CU. Rope off critical path (v9), (k,15-k) pairing retained.
__global__ __launch_bounds__(256) void attn_kernel(const bf16* __restrict__ qkv,
                                                   const bf16* __restrict__ vt,
                                                   bf16* __restrict__ y) {
  __shared__ bf16 sk[2][64 * 72];
  __shared__ bf16 skr[2][64 * 72];
  __shared__ bf16 sv[2][64 * 72];
  __shared__ bf16 pl[4][16 * 72];
  int t = threadIdx.x, l = t & 63, w = t >> 6;
  int blk = blockIdx.x;  // 512
  int idx = blk & 255;
  int it = (blk < 256) ? (idx >> 5) : (15 - (idx >> 5));  // balanced (k,15-k) CU pairs
  int r5 = idx & 31;
  int b = r5 >> 4;
  int h = r5 & 15;
  int i_base = it * 64 + w * 16;
  int lm = l & 15, lq = l >> 4;
  const float scale = 0.125f;

  size_t hq = (size_t)h * DH_;
  size_t qrow = (size_t)(b * C_ + i_base + lm) * (3 * D_) + hq;
  bf16x8 qp[2], qrf[2];
  float cq = (float)(i_base + lm);
#pragma unroll
  for (int kk = 0; kk < 2; ++kk) {
    qp[kk] = *(const bf16x8*)(qkv + qrow + kk * 32 + lq * 8);
#pragma unroll
    for (int j = 0; j < 4; ++j) {
      float ip = (float)(kk * 16 + lq * 4 + j);
      float ang = cq * rope_theta(ip);
      float sv_, cv_;
      __sincosf(ang, &sv_, &cv_);
      float qe = (float)qp[kk][2 * j], qo = (float)qp[kk][2 * j + 1];
      qrf[kk][2 * j] = (bf16)(qe * cv_ + qo * sv_);
      qrf[kk][2 * j + 1] = (bf16)(qo * cv_ - qe * sv_);
    }
  }

  float den[4] = {0.f, 0.f, 0.f, 0.f};
  f32x4 yacc[4] = {};
  int i_max = i_base + 15;
  size_t kbase = (size_t)(b * C_) * (3 * D_) + D_ + hq;
  size_t vtbase = (size_t)((b * H_ + h) * DH_) * C_;
  int sr = t >> 3;
  int sc = (t & 7) * 8;
  float th0 = rope_theta((float)((sc >> 1) + 0));
  float th1 = rope_theta((float)((sc >> 1) + 1));
  float th2 = rope_theta((float)((sc >> 1) + 2));
  float th3 = rope_theta((float)((sc >> 1) + 3));

  int4 pk0, pk1, pv0, pv1, rk0, rk1;
#define FETCH_TILE(J0)                                                          \
  pk0 = *(const int4*)(qkv + kbase + (size_t)((J0) + sr) * (3 * D_) + sc);      \
  pk1 = *(const int4*)(qkv + kbase + (size_t)((J0) + 32 + sr) * (3 * D_) + sc); \
  pv0 = *(const int4*)(vt + vtbase + (size_t)sr * C_ + (J0) + sc);              \
  pv1 = *(const int4*)(vt + vtbase + (size_t)(32 + sr) * C_ + (J0) + sc);

#define ROTP(KV, RV, P)                                       \
  {                                                           \
    float e = (float)KV[2 * P], o = (float)KV[2 * P + 1];     \
    RV[2 * P] = (bf16)(e * c_ + o * s_);                      \
    RV[2 * P + 1] = (bf16)(o * c_ - e * s_);                  \
  }
#define ROTATE(J0)                                            \
  {                                                           \
    bf16x8 k0 = *(bf16x8*)&pk0, k1 = *(bf16x8*)&pk1;          \
    bf16x8 r0, r1;                                            \
    float jA = (float)((J0) + sr), jB = (float)((J0) + 32 + sr); \
    float s_, c_;                                             \
    __sincosf(jA * th0, &s_, &c_); ROTP(k0, r0, 0)            \
    __sincosf(jA * th1, &s_, &c_); ROTP(k0, r0, 1)            \
    __sincosf(jA * th2, &s_, &c_); ROTP(k0, r0, 2)            \
    __sincosf(jA * th3, &s_, &c_); ROTP(k0, r0, 3)            \
    __sincosf(jB * th0, &s_, &c_); ROTP(k1, r1, 0)            \
    __sincosf(jB * th1, &s_, &c_); ROTP(k1, r1, 1)            \
    __sincosf(jB * th2, &s_, &c_); ROTP(k1, r1, 2)            \
    __sincosf(jB * th3, &s_, &c_); ROTP(k1, r1, 3)            \
    rk0 = *(int4*)&r0;                                        \
    rk1 = *(int4*)&r1;                                        \
  }

  FETCH_TILE(0)
  ROTATE(0)

  for (int j0 = 0; j0 < C_; j0 += 64) {
    int bu = (j0 >> 6) & 1;
    *(int4*)(&sk[bu][0] + sr * 72 + sc) = pk0;
    *(int4*)(&sk[bu][0] + (32 + sr) * 72 + sc) = pk1;
    *(int4*)(&skr[bu][0] + sr * 72 + sc) = rk0;
    *(int4*)(&skr[bu][0] + (32 + sr) * 72 + sc) = rk1;
    *(int4*)(&sv[bu][0] + sr * 72 + sc) = pv0;
    *(int4*)(&sv[bu][0] + (32 + sr) * 72 + sc) = pv1;
    __syncthreads();  // single barrier per tile: publishes buf[bu]
    if (j0 + 64 < C_) {
      FETCH_TILE(j0 + 64)
    }
    // denominator: unrotated q.k over all j
#pragma unroll
    for (int js = 0; js < 64; js += 16) {
      bf16x8 kf0 = *(const bf16x8*)(&sk[bu][0] + (js + lm) * 72 + lq * 8);
      bf16x8 kf1 = *(const bf16x8*)(&sk[bu][0] + (js + lm) * 72 + 32 + lq * 8);
      f32x4 s = {0.f, 0.f, 0.f, 0.f};
      s = mfma16(qp[0], kf0, s);
      s = mfma16(qp[1], kf1, s);
#pragma unroll
      for (int r = 0; r < 4; ++r) den[r] += __expf(s[r] * scale);
    }
    // numerator + PV: causal tiles only (wave-uniform guard)
    if (j0 <= i_max) {
#pragma unroll
      for (int js = 0; js < 64; js += 16) {
        bf16x8 kf0 = *(const bf16x8*)(&skr[bu][0] + (js + lm) * 72 + lq * 8);
        bf16x8 kf1 = *(const bf16x8*)(&skr[bu][0] + (js + lm) * 72 + 32 + lq * 8);
        f32x4 s = {0.f, 0.f, 0.f, 0.f};
        s = mfma16(qrf[0], kf0, s);
        s = mfma16(qrf[1], kf1, s);
#pragma unroll
        for (int r = 0; r < 4; ++r) {
          int jg = j0 + js + lm;
          int ig = i_base + lq * 4 + r;
          float p = (jg <= ig) ? __expf(s[r] * scale) : 0.0f;
          pl[w][(lq * 4 + r) * 72 + js + lm] = (bf16)p;
        }
      }
      __builtin_amdgcn_wave_barrier();
      bf16x8 pf0 = *(const bf16x8*)(pl[w] + lm * 72 + lq * 8);
      bf16x8 pf1 = *(const bf16x8*)(pl[w] + lm * 72 + 32 + lq * 8);
#pragma unroll
      for (int tt = 0; tt < 4; ++tt) {
        bf16x8 vf0 = *(const bf16x8*)(&sv[bu][0] + (tt * 16 + lm) * 72 + lq * 8);
        bf16x8 vf1 = *(const bf16x8*)(&sv[bu][0] + (tt * 16 + lm) * 72 + 32 + lq * 8);
        yacc[tt] = mfma16(pf0, vf0, mfma16(pf1, vf1, yacc[tt]));
      }
      __builtin_amdgcn_wave_barrier();
    }
    // rotate NEXT tile's K (loads landed during compute; pure VALU, off the serial path)
    if (j0 + 64 < C_) {
      ROTATE(j0 + 64)
    }
  }
#undef FETCH_TILE
#undef ROTATE
#undef ROTP
  // normalize in-register and write y directly (no combine pass)
  float inv[4];
#pragma unroll
  for (int r = 0; r < 4; ++r) {
    float d = den[r];
    d += __shfl_xor(d, 1, 64);
    d += __shfl_xor(d, 2, 64);
    d += __shfl_xor(d, 4, 64);
    d += __shfl_xor(d, 8, 64);
    inv[r] = 1.0f / d;
  }
#pragma unroll
  for (int tt = 0; tt < 4; ++tt)
#pragma unroll
    for (int r = 0; r < 4; ++r) {
      int ig = i_base + lq * 4 + r;
      y[(size_t)(b * C_ + ig) * D_ + hq + tt * 16 + lm] = (bf16)(yacc[tt][r] * inv[r]);
    }
}

extern "C" void kernel_launch(void* const* d_in, const int* in_sizes, int n_in,
                              void* d_out, int out_size, void* d_ws, size_t ws_size,
                              hipStream_t stream) {
  const float* x = (const float*)d_in[0];
  const float* rms_w = (const float*)d_in[1];
  const float* rms_b = (const float*)d_in[2];
  const float* Wqkv = (const float*)d_in[3];
  const float* Wout = (const float*)d_in[4];
  const float* bout = (const float*)d_in[5];
  const float* Wf = (const float*)d_in[6];
  const float* bfp = (const float*)d_in[7];
  const float* Ww = (const float*)d_in[8];
  const float* bw = (const float*)d_in[9];
  const float* Wv = (const float*)d_in[10];
  const float* bv = (const float*)d_in[11];
  const float* beta = (const float*)d_in[12];
  float* out = (float*)d_out;

  bf16* ws = (bf16*)d_ws;
  const size_t DD = (size_t)D_ * D_;
  const size_t MC = (size_t)B_ * C_;
  bf16* wb = ws;            // 7DD: Wqkv(3), Wout, Wf, Ww, Wv
  bf16* x1 = ws + 7 * DD;
  bf16* qkv = ws + 9 * DD;
  bf16* vt = ws + 15 * DD;
  bf16* x2 = ws + 17 * DD;
  bf16* x3 = ws + 19 * DD;
  bf16* hbuf = ws + 21 * DD;
  bf16* y = (bf16*)d_out;   // bf16 y inside fp32 d_out; consumed before final write

  cvt_rms_kernel<<<7 * 1024 + MC, 256, 0, stream>>>(Wqkv, Wout, Wf, Ww, Wv, wb, x, rms_w,
                                                    rms_b, x1);
  gemm_qkv_kernel<<<dim3(3 * D_ / 64, MC / 128), 256, 0, stream>>>(x1, wb, qkv, vt);
  attn_kernel<<<B_ * H_ * 16, 256, 0, stream>>>(qkv, vt, y);
  gemm_lds<64, 64><<<dim3(D_ / 64, MC / 64), 256, 0, stream>>>(
      y, wb + 3 * DD, bout, x1, x2, MC, D_, D_);
  rmsnorm_bf16_kernel<<<MC, 256, 0, stream>>>(x2, rms_w, rms_b, x3);
  gemm_lds<64, 64><<<dim3(D_ / 64, MC / 64), 256, 0, stream>>>(
      x3, wb + 4 * DD, bfp, nullptr, hbuf, MC, D_, D_);
  gemm_ffn_kernel<<<dim3(D_ / 64, MC / 64), 256, 0, stream>>>(
      hbuf, wb + 5 * DD, wb + 6 * DD, bw, bv, x3, beta, out);
}